// Round 7
// baseline (6759.163 us; speedup 1.0000x reference)
//
#include <hip/hip_runtime.h>
#include <stdint.h>

// ---------------------------------------------------------------------------
// MRT seq2seq sampler for MI355X. Round 7.
// R4: passed 11.4ms. R6 (parallel reduce + oproj retile): passed 6.55ms.
// R6 counters: k_gemm_logits 86.6us x37 = 3.2ms (half of total), 37.8 TF
// fp32 (24% of peak) at VALUBusy 72%, 4.1M LDS bank conflicts -> VALU-issue
// bound with thin 4x4 microtile. This round: retile to 64x128 / BK=32 with
// 4x8 microtile (32 FMA per 3 ds_read_b128), conflict-engineered LDS strides
// (As 76, Ws 132, split col-quads {tc*4, 64+tc*4}), grid(125,4)=500 blocks.
// Per-output K-order unchanged (ascending k, fused FMA) -> logits
// BIT-IDENTICAL to R6; argmax/tie-break exact; only tile-partial sumexp
// grouping changes (tolerant path; R6 already moved it, absmax 0.0).
// RNG: JAX threefry2x32, threefry_partitionable=True. VERIFIED r4/r6.
// ---------------------------------------------------------------------------

#define DINLINE __device__ __forceinline__

DINLINE uint32_t rotl32(uint32_t x, int r) { return (x << r) | (x >> (32 - r)); }

// JAX threefry2x32 (jax/_src/prng.py), 20 rounds.
DINLINE void tf2x32(uint32_t k0, uint32_t k1, uint32_t x0, uint32_t x1,
                    uint32_t& y0, uint32_t& y1)
{
  const uint32_t ks2 = k0 ^ k1 ^ 0x1BD11BDAu;
#define TFR(r) { x0 += x1; x1 = rotl32(x1, r); x1 ^= x0; }
  x0 += k0; x1 += k1;
  TFR(13) TFR(15) TFR(26) TFR(6)
  x0 += k1; x1 += ks2 + 1u;
  TFR(17) TFR(29) TFR(16) TFR(24)
  x0 += ks2; x1 += k0 + 2u;
  TFR(13) TFR(15) TFR(26) TFR(6)
  x0 += k0; x1 += k1 + 3u;
  TFR(17) TFR(29) TFR(16) TFR(24)
  x0 += k1; x1 += ks2 + 4u;
  TFR(13) TFR(15) TFR(26) TFR(6)
  x0 += ks2; x1 += k0 + 5u;
#undef TFR
  y0 = x0; y1 = x1;
}

// partitionable random_bits (32-bit): counter = (hi=0, lo=flat), bits = y0^y1
// then uniform(minval=tiny,1) -> gumbel, matching jax gumbel()/uniform() fp32.
DINLINE float gumbel32(uint32_t k0, uint32_t k1, uint32_t flat)
{
  uint32_t b1, b2; tf2x32(k0, k1, 0u, flat, b1, b2);
  const uint32_t bits = b1 ^ b2;
  const float f = __uint_as_float((bits >> 9) | 0x3F800000u) - 1.0f;
  const float u = (f == 0.0f) ? 1.17549435e-38f : f; // max(tiny, f*1+tiny)
  return -logf(-logf(u));
}

DINLINE float sigmoidf_(float x) { return 1.0f / (1.0f + expf(-x)); }

#define PSTRIDE 128   // partials per-row stride (125 col-tiles, padded)

// ---------------------------------------------------------------------------
// init: zero encoder h0
__global__ void k_init(float* __restrict__ henc0)
{
  const int i = blockIdx.x * 256 + threadIdx.x;
  if (i < 1024) henc0[i] = 0.0f;
}

// ---------------------------------------------------------------------------
// Encoder: xg[s*2+b][g] = emb_src[src[s][b]] @ Wex + be   (48 x 1536, K=512)
__global__ __launch_bounds__(256) void k_enc_xg(
    const int* __restrict__ src, const float* __restrict__ emb,
    const float* __restrict__ Wex, const float* __restrict__ be,
    float* __restrict__ xg)
{
  __shared__ float xl[512];
  const int rrow = blockIdx.x;         // s*2+b
  const int tid = threadIdx.x;
  const int tokv = src[rrow];
  for (int i = tid; i < 512; i += 256) xl[i] = emb[(size_t)tokv * 512 + i];
  __syncthreads();
  const int j = blockIdx.y * 256 + tid;
  float a = be[j];
  for (int k = 0; k < 512; ++k) a += xl[k] * Wex[(size_t)k * 1536 + j];
  xg[(size_t)rrow * 1536 + j] = a;
}

// Encoder recurrent step: hout = GRU(x_s, hprev). grid(4) x 256, 2 rows x 128 j.
__global__ __launch_bounds__(256) void k_enc_step(
    const float* __restrict__ hprev, const float* __restrict__ xg,
    const float* __restrict__ Weh, float* __restrict__ hout)
{
  __shared__ float hp[2][512];
  const int tid = threadIdx.x;
  for (int i = tid; i < 1024; i += 256) hp[i >> 9][i & 511] = hprev[i];
  __syncthreads();
  const int row = tid >> 7;                       // 0..1
  const int j = blockIdx.x * 128 + (tid & 127);   // 0..511
  float gz = 0.f, gr = 0.f, gn = 0.f;
  for (int k = 0; k < 512; ++k) {
    const float h = hp[row][k];
    const float* w = Weh + (size_t)k * 1536 + j;
    gz += h * w[0]; gr += h * w[512]; gn += h * w[1024];
  }
  const float xz = xg[row * 1536 + j];
  const float xr = xg[row * 1536 + j + 512];
  const float xn = xg[row * 1536 + j + 1024];
  const float z = sigmoidf_(xz + gz);
  const float r = sigmoidf_(xr + gr);
  const float n = tanhf(xn + r * gn);
  hout[row * 512 + j] = (1.0f - z) * n + z * hp[row][j];
}

// Decoder state init: h = repeat(hT), tok=BOS, dead=0, acc=0, match=1 (BOS hit)
__global__ void k_dec_init(const float* __restrict__ ctx23, float* __restrict__ hA,
                           int* __restrict__ tok, float* __restrict__ dead,
                           float* __restrict__ acc, int* __restrict__ mc)
{
  const int i = blockIdx.x * 256 + threadIdx.x;
  if (i < 200 * 512) {
    const int bn = i >> 9, k = i & 511, b = bn / 100;
    hA[i] = ctx23[b * 512 + k];
  }
  if (i < 200) { tok[i] = 2; dead[i] = 0.f; acc[i] = 0.f; mc[i] = 1; }
}

// ---------------------------------------------------------------------------
// gates GEMM: z=0 -> gx = emb_tgt[tok] @ Wdx + bd ; z=1 -> gh = h @ Wdh
// tiles 32x32, BK=32, 2x2 microtile. grid(48, 7, 2) x 256.
__global__ __launch_bounds__(256) void k_gates(
    const float* __restrict__ hprev, const float* __restrict__ emb_tgt,
    const int* __restrict__ tok,
    const float* __restrict__ Wdx, const float* __restrict__ Wdh,
    const float* __restrict__ bd,
    float* __restrict__ gx, float* __restrict__ gh)
{
  __shared__ float As[32][33];
  __shared__ float Ws[32][32];
  const int tid = threadIdx.x;
  const int nt = blockIdx.x, mt = blockIdx.y, zz = blockIdx.z;
  const int c0 = nt * 32;
  const float* __restrict__ Bw = zz ? Wdh : Wdx;
  float a00 = 0.f, a01 = 0.f, a10 = 0.f, a11 = 0.f;
  const int tr = tid >> 4, tc = tid & 15;
  for (int k0 = 0; k0 < 512; k0 += 32) {
    {
      const int r = tid >> 3, kk = (tid & 7) << 2;
      const int row = mt * 32 + r;
      float4 v = make_float4(0.f, 0.f, 0.f, 0.f);
      if (row < 200) {
        const int k = k0 + kk;
        if (zz == 0) v = *(const float4*)(emb_tgt + (size_t)tok[row] * 512 + k);
        else         v = *(const float4*)(hprev + (size_t)row * 512 + k);
      }
      As[kk + 0][r] = v.x; As[kk + 1][r] = v.y; As[kk + 2][r] = v.z; As[kk + 3][r] = v.w;
    }
    {
      const int kr = tid >> 3, cc = (tid & 7) << 2;
      *(float4*)&Ws[kr][cc] = *(const float4*)(Bw + (size_t)(k0 + kr) * 1536 + c0 + cc);
    }
    __syncthreads();
#pragma unroll
    for (int kk = 0; kk < 32; ++kk) {
      const float a0 = As[kk][tr * 2], a1 = As[kk][tr * 2 + 1];
      const float w0 = Ws[kk][tc * 2], w1 = Ws[kk][tc * 2 + 1];
      a00 += a0 * w0; a01 += a0 * w1; a10 += a1 * w0; a11 += a1 * w1;
    }
    __syncthreads();
  }
  float* __restrict__ outp = zz ? gh : gx;
  const int row0 = mt * 32 + tr * 2, col0 = c0 + tc * 2;
  const float b0 = zz ? 0.f : bd[col0];
  const float b1 = zz ? 0.f : bd[col0 + 1];
  if (row0 < 200) {
    outp[(size_t)row0 * 1536 + col0]     = a00 + b0;
    outp[(size_t)row0 * 1536 + col0 + 1] = a01 + b1;
  }
  if (row0 + 1 < 200) {
    outp[(size_t)(row0 + 1) * 1536 + col0]     = a10 + b0;
    outp[(size_t)(row0 + 1) * 1536 + col0 + 1] = a11 + b1;
  }
}

// ---------------------------------------------------------------------------
// Per-row: GRU combine -> h_t, then attention softmax over S=24 -> context c.
// grid(200) x 256.
__global__ __launch_bounds__(256) void k_update_attn(
    const float* __restrict__ gx, const float* __restrict__ gh,
    const float* __restrict__ hprev, float* __restrict__ hcur,
    const float* __restrict__ ctx, const int* __restrict__ src,
    float* __restrict__ cc)
{
  const int bn = blockIdx.x, b = bn / 100;
  const int tid = threadIdx.x;
  __shared__ float hn[512];
  __shared__ float sc[24];
  const float* gxr = gx + (size_t)bn * 1536;
  const float* ghr = gh + (size_t)bn * 1536;
  const float* hpr = hprev + (size_t)bn * 512;
  for (int j = tid; j < 512; j += 256) {
    const float z = sigmoidf_(gxr[j] + ghr[j]);
    const float r = sigmoidf_(gxr[j + 512] + ghr[j + 512]);
    const float n = tanhf(gxr[j + 1024] + r * ghr[j + 1024]);
    const float h = (1.0f - z) * n + z * hpr[j];
    hn[j] = h;
    hcur[(size_t)bn * 512 + j] = h;
  }
  __syncthreads();
  const int w = tid >> 6, lane = tid & 63;
  for (int s = w; s < 24; s += 4) {
    const float* cr = ctx + (size_t)(s * 2 + b) * 512;
    float v = 0.f;
#pragma unroll
    for (int m = 0; m < 8; ++m) { const int k = lane + 64 * m; v += hn[k] * cr[k]; }
#pragma unroll
    for (int m2 = 32; m2 >= 1; m2 >>= 1) v += __shfl_xor(v, m2, 64);
    if (lane == 0) sc[s] = (src[s * 2 + b] == 0) ? -1e9f : v;  // pad mask (NEG_INF)
  }
  __syncthreads();
  float mx = -3.0e38f;
#pragma unroll
  for (int s = 0; s < 24; ++s) mx = fmaxf(mx, sc[s]);
  float ez[24]; float sum = 0.f;
#pragma unroll
  for (int s = 0; s < 24; ++s) { ez[s] = expf(sc[s] - mx); sum += ez[s]; }
#pragma unroll
  for (int s = 0; s < 24; ++s) ez[s] = ez[s] / sum;  // attn, rounded like reference
  for (int j = tid; j < 512; j += 256) {
    float a = 0.f;
#pragma unroll
    for (int s = 0; s < 24; ++s) a += ez[s] * ctx[(size_t)(s * 2 + b) * 512 + j];
    cc[(size_t)bn * 512 + j] = a;
  }
}

// ---------------------------------------------------------------------------
// o = tanh([h|c] @ Wo + bo). 16x32 tiles, K=1024, 2 outputs/thread.
// grid(16, 13) x 256 = 208 blocks. Bit-identical ob vs r4 (K-order unchanged).
__global__ __launch_bounds__(256) void k_oproj(
    const float* __restrict__ hcur, const float* __restrict__ ccx,
    const float* __restrict__ Wo, const float* __restrict__ bo,
    float* __restrict__ ob)
{
  __shared__ float As[32][17];   // [kk][row], 17 stride: conflict-free
  __shared__ float Ws[32][32];   // [kk][col]
  const int tid = threadIdx.x;
  const int nt = blockIdx.x, mt = blockIdx.y;
  const int c0 = nt * 32, r0 = mt * 16;
  const int tr = tid >> 4, tc = tid & 15;      // row 0..15, col-pair 0..15
  float a0 = 0.f, a1 = 0.f;
  for (int k0 = 0; k0 < 1024; k0 += 32) {
    {
      const int kk = tid & 31;                 // 0..31
      const int rr = tid >> 5;                 // 0..7
      const int k = k0 + kk;
      const float* srcp = (k < 512) ? (hcur + k) : (ccx + (k - 512));
      for (int r = rr; r < 16; r += 8) {
        const int row = r0 + r;
        As[kk][r] = (row < 200) ? srcp[(size_t)row * 512] : 0.f;
      }
    }
    {
      const int kr = tid >> 3, cc = (tid & 7) << 2;
      *(float4*)&Ws[kr][cc] = *(const float4*)(Wo + (size_t)(k0 + kr) * 512 + c0 + cc);
    }
    __syncthreads();
#pragma unroll
    for (int kk = 0; kk < 32; ++kk) {
      const float a = As[kk][tr];
      a0 += a * Ws[kk][tc * 2];
      a1 += a * Ws[kk][tc * 2 + 1];
    }
    __syncthreads();
  }
  const int row = r0 + tr, col = c0 + tc * 2;
  if (row < 200) {
    ob[(size_t)row * 512 + col]     = tanhf(a0 + bo[col]);
    ob[(size_t)row * 512 + col + 1] = tanhf(a1 + bo[col + 1]);
  }
}

// ---------------------------------------------------------------------------
// logits = o @ Wg + bg, fused gumbel + per-tile argmax / max / sumexp partials.
// R7 retile: 64x128 tile, BK=32, 4x8 microtile (cols split {tc*4, 64+tc*4}).
// grid(125, 4) x 256 = 500 blocks (~2/CU). Never stores logits.
// Per-output FMA sequence (ascending k) IDENTICAL to r6 -> bit-exact logits.
// LDS: As stride 76 (write ~2-way), Ws stride 132 (read/write 2-way = free).
__global__ __launch_bounds__(256) void k_gemm_logits(
    const float* __restrict__ Ao, const float* __restrict__ Wg,
    const float* __restrict__ bg, int t,
    float* __restrict__ p_bv, float* __restrict__ p_bl,
    float* __restrict__ p_ml, float* __restrict__ p_se, int* __restrict__ p_bi)
{
  __shared__ float As[32][76];    // [kk][row0..63], stride 76 (304B, 16B-aligned)
  __shared__ float Ws[32][132];   // [kk][col0..127], stride 132 (528B, 16B-aligned)
  const int tid = threadIdx.x;
  const int nt = blockIdx.x, mt = blockIdx.y;
  const int c0 = nt * 128, r0 = mt * 64;
  const int tr = tid >> 4, tc = tid & 15;     // tr 0..15 (4 rows each), tc 0..15
  float acc[4][8] = {};
  for (int k0 = 0; k0 < 512; k0 += 32) {
    // stage A: 64 rows x 32 k. Coalesced float4 per row-chunk, scatter to [kk][row].
    {
      const int kq = (tid & 7) << 2;          // k offset 0,4,..,28
#pragma unroll
      for (int p = 0; p < 2; ++p) {
        const int r = (tid >> 3) + p * 32;    // 0..63
        const int row = r0 + r;
        float4 v = make_float4(0.f, 0.f, 0.f, 0.f);
        if (row < 200) v = *(const float4*)(Ao + (size_t)row * 512 + k0 + kq);
        As[kq + 0][r] = v.x; As[kq + 1][r] = v.y;
        As[kq + 2][r] = v.z; As[kq + 3][r] = v.w;
      }
    }
    // stage W: 32 k x 128 cols. 4 consecutive float4 per thread, coalesced.
    {
      const int kr = tid >> 3, cc = (tid & 7) << 4;
      const float* s = Wg + (size_t)(k0 + kr) * 16000 + c0 + cc;
      *(float4*)&Ws[kr][cc + 0]  = *(const float4*)(s + 0);
      *(float4*)&Ws[kr][cc + 4]  = *(const float4*)(s + 4);
      *(float4*)&Ws[kr][cc + 8]  = *(const float4*)(s + 8);
      *(float4*)&Ws[kr][cc + 12] = *(const float4*)(s + 12);
    }
    __syncthreads();
#pragma unroll
    for (int kk = 0; kk < 32; ++kk) {
      const float4 a  = *(const float4*)&As[kk][tr << 2];
      const float4 w0 = *(const float4*)&Ws[kk][tc << 2];
      const float4 w1 = *(const float4*)&Ws[kk][64 + (tc << 2)];
      const float av[4] = {a.x, a.y, a.z, a.w};
      const float wv[8] = {w0.x, w0.y, w0.z, w0.w, w1.x, w1.y, w1.z, w1.w};
#pragma unroll
      for (int i = 0; i < 4; ++i)
#pragma unroll
        for (int j = 0; j < 8; ++j)
          acc[i][j] += av[i] * wv[j];
    }
    __syncthreads();
  }
  // epilogue: gumbel + per-row tile reductions over the 128-col tile.
  // Thread's cols ascending: tc*4+j (j 0..3), then 64+tc*4+j (j 0..3).
  uint32_t sk0, sk1; tf2x32(0u, 42u, 0u, (uint32_t)t, sk0, sk1); // split(key(42))[t]
  const float NEGINF = -3.0e38f;
#pragma unroll
  for (int i = 0; i < 4; ++i) {
    const int row = r0 + (tr << 2) + i;
    const bool valid = (row < 200);
    float logit[8];
    float tmax = NEGINF;
#pragma unroll
    for (int j = 0; j < 8; ++j) {
      const int col = c0 + ((j < 4) ? ((tc << 2) + j) : (64 + (tc << 2) + (j - 4)));
      logit[j] = acc[i][j] + bg[col];
      tmax = fmaxf(tmax, logit[j]);
    }
    if (!valid) tmax = NEGINF;
#pragma unroll
    for (int m = 1; m <= 8; m <<= 1) tmax = fmaxf(tmax, __shfl_xor(tmax, m, 64));
    float se = 0.f, bv = NEGINF, bl = 0.f; int bi = 0;
    if (valid) {
#pragma unroll
      for (int j = 0; j < 8; ++j) {
        const int col = c0 + ((j < 4) ? ((tc << 2) + j) : (64 + (tc << 2) + (j - 4)));
        se += expf(logit[j] - tmax);
        const float g = gumbel32(sk0, sk1, (uint32_t)(row * 16000 + col));
        const float v = logit[j] + g;
        if (v > bv) { bv = v; bi = col; bl = logit[j]; }  // first-occurrence ties
      }
    }
#pragma unroll
    for (int m = 1; m <= 8; m <<= 1) {
      const float ov = __shfl_xor(bv, m, 64);
      const int   oi = __shfl_xor(bi, m, 64);
      const float ol = __shfl_xor(bl, m, 64);
      se += __shfl_xor(se, m, 64);
      if (ov > bv || (ov == bv && oi < bi)) { bv = ov; bi = oi; bl = ol; }
    }
    if (tc == 0 && valid) {
      const size_t p = (size_t)row * PSTRIDE + nt;   // bn-major for coalesced reduce
      p_bv[p] = bv; p_bl[p] = bl; p_ml[p] = tmax; p_se[p] = se; p_bi[p] = bi;
    }
  }
}

// ---------------------------------------------------------------------------
// Parallel combine of 125 tile-partials per row. grid(200) x 64 (one wave/bn).
// Global max M: exact. Argmax: exact (max + lower-index tie-break).
// Denominator S: tree order (tolerant path; r6 already reordered, absmax 0.0).
__global__ void k_reduce_sample(
    const float* __restrict__ p_bv, const float* __restrict__ p_bl,
    const float* __restrict__ p_ml, const float* __restrict__ p_se,
    const int* __restrict__ p_bi,
    const int* __restrict__ tgt, int t,
    int* __restrict__ tok, float* __restrict__ dead,
    float* __restrict__ acc, int* __restrict__ mc)
{
  const int bn = blockIdx.x;
  const int lane = threadIdx.x;                 // 0..63
  const size_t base = (size_t)bn * PSTRIDE;
  float M = -3.0e38f;
  for (int nt = lane; nt < 125; nt += 64) M = fmaxf(M, p_ml[base + nt]);
#pragma unroll
  for (int m = 32; m >= 1; m >>= 1) M = fmaxf(M, __shfl_xor(M, m, 64));
  float S = 0.f, bv = -3.0e38f, bl = 0.f;
  int bi = 0x7FFFFFFF;
  for (int nt = lane; nt < 125; nt += 64) {
    S += p_se[base + nt] * expf(p_ml[base + nt] - M);
    const float v = p_bv[base + nt];
    const int   i = p_bi[base + nt];
    if (v > bv || (v == bv && i < bi)) { bv = v; bi = i; bl = p_bl[base + nt]; }
  }
#pragma unroll
  for (int m = 32; m >= 1; m >>= 1) {
    S += __shfl_xor(S, m, 64);
    const float ov = __shfl_xor(bv, m, 64);
    const int   oi = __shfl_xor(bi, m, 64);
    const float ol = __shfl_xor(bl, m, 64);
    if (ov > bv || (ov == bv && oi < bi)) { bv = ov; bi = oi; bl = ol; }
  }
  if (lane == 0) {
    const float dv = dead[bn];
    acc[bn] += ((bl - M) - logf(S)) * (1.0f - dv);   // logp[nxt]*(1-dead)
    const int b = bn / 100;
    if (t + 1 < 26) {
      const int tv = tgt[(t + 1) * 2 + b];
      if (tv != 0 && bi == tv) mc[bn] += 1;
    }
    dead[bn] = fmaxf(dv, (bi == 3) ? 1.0f : 0.0f);   // EOS=3
    tok[bn] = bi;
  }
}

// ---------------------------------------------------------------------------
// Final: bleu, per-batch softmax over N=100 of acc*ALPHA, 4 scalar outputs.
__global__ __launch_bounds__(256) void k_final(
    const float* __restrict__ accb, const int* __restrict__ mc,
    const int* __restrict__ tgt, float* __restrict__ out)
{
  __shared__ int ncw[4];
  __shared__ float LS[2], SS[2], QS[2];
  const int tid = threadIdx.x, w = tid >> 6, lane = tid & 63;
  int c0c = 0, c1c = 0;
  for (int tt = 0; tt < 26; ++tt) {
    c0c += (tgt[tt * 2] != 0);
    c1c += (tgt[tt * 2 + 1] != 0);
  }
  int nc = (tid < 200) ? mc[tid] : 0;
#pragma unroll
  for (int m = 32; m >= 1; m >>= 1) nc += __shfl_xor(nc, m, 64);
  if (lane == 0) ncw[w] = nc;
  if (w < 2) {
    const int b = w;
    const float denom = fmaxf((float)(b == 0 ? c0c : c1c), 1.0f);
    const float e0 = accb[b * 100 + lane] * 0.005f;
    const float e1 = (lane < 36) ? accb[b * 100 + 64 + lane] * 0.005f : -3.0e38f;
    float mx = fmaxf(e0, e1);
#pragma unroll
    for (int m = 32; m >= 1; m >>= 1) mx = fmaxf(mx, __shfl_xor(mx, m, 64));
    float S = 0.f, L = 0.f, Q = 0.f;
    {
      const float p = expf(e0 - mx);
      const float bl = (float)mc[b * 100 + lane] / denom;
      S += p; L += bl * p; Q += bl * bl * p;
    }
    if (lane < 36) {
      const float p = expf(e1 - mx);
      const float bl = (float)mc[b * 100 + 64 + lane] / denom;
      S += p; L += bl * p; Q += bl * bl * p;
    }
#pragma unroll
    for (int m = 32; m >= 1; m >>= 1) {
      S += __shfl_xor(S, m, 64);
      L += __shfl_xor(L, m, 64);
      Q += __shfl_xor(Q, m, 64);
    }
    if (lane == 0) { LS[b] = L; SS[b] = S; QS[b] = Q; }
  }
  __syncthreads();
  if (tid == 0) {
    out[0] = -(LS[0] / SS[0] + LS[1] / SS[1]);  // totalLoss
    out[1] =  QS[0] / SS[0] + QS[1] / SS[1];    // secondMoment
    out[2] = 100.0f * (float)(c0c + c1c);       // numWords
    out[3] = (float)(ncw[0] + ncw[1] + ncw[2] + ncw[3]);  // numCorrect
  }
}

// ---------------------------------------------------------------------------
extern "C" void kernel_launch(void* const* d_in, const int* in_sizes, int n_in,
                              void* d_out, int out_size, void* d_ws, size_t ws_size,
                              hipStream_t stream)
{
  (void)in_sizes; (void)n_in; (void)out_size; (void)ws_size;
  const int*   src     = (const int*)  d_in[0];
  const int*   tgt     = (const int*)  d_in[1];
  // d_in[2] lengths: unused by the reference math
  const float* emb_src = (const float*)d_in[3];
  const float* emb_tgt = (const float*)d_in[4];
  const float* Wex     = (const float*)d_in[5];
  const float* Weh     = (const float*)d_in[6];
  const float* be      = (const float*)d_in[7];
  const float* Wdx     = (const float*)d_in[8];
  const float* Wdh     = (const float*)d_in[9];
  const float* bd      = (const float*)d_in[10];
  const float* Wo      = (const float*)d_in[11];
  const float* bo      = (const float*)d_in[12];
  const float* Wg      = (const float*)d_in[13];
  const float* bg      = (const float*)d_in[14];
  float* out = (float*)d_out;

  float* W = (float*)d_ws;
  size_t off = 0;
  auto alloc = [&](size_t n) { float* p = W + off; off += n; return p; };
  float* henc0 = alloc(1024);
  float* xgE   = alloc(48 * 1536);
  float* ctx   = alloc(24 * 1024);
  float* hA    = alloc(200 * 512);
  float* hB    = alloc(200 * 512);
  float* gx    = alloc(200 * 1536);
  float* gh    = alloc(200 * 1536);
  float* cc    = alloc(200 * 512);
  float* ob    = alloc(200 * 512);
  float* p_bv  = alloc(200 * PSTRIDE);
  float* p_bl  = alloc(200 * PSTRIDE);
  float* p_ml  = alloc(200 * PSTRIDE);
  float* p_se  = alloc(200 * PSTRIDE);
  int*   p_bi  = (int*)alloc(200 * PSTRIDE);
  int*   tok   = (int*)alloc(200);
  float* dead  = alloc(200);
  float* accb  = alloc(200);
  int*   mc    = (int*)alloc(200);
  // total ~3.1 MB of d_ws

  // --- encoder ---
  k_init<<<dim3(4), dim3(256), 0, stream>>>(henc0);
  k_enc_xg<<<dim3(48, 6), dim3(256), 0, stream>>>(src, emb_src, Wex, be, xgE);
  for (int s = 0; s < 24; ++s) {
    const float* hp = (s == 0) ? henc0 : (ctx + (size_t)(s - 1) * 1024);
    k_enc_step<<<dim3(4), dim3(256), 0, stream>>>(
        hp, xgE + (size_t)s * 2 * 1536, Weh, ctx + (size_t)s * 1024);
  }
  k_dec_init<<<dim3(400), dim3(256), 0, stream>>>(ctx + 23 * 1024, hA, tok, dead, accb, mc);

  // --- decoder: 37 sequential sampled steps ---
  for (int t = 0; t < 37; ++t) {
    float* hp = (t & 1) ? hB : hA;
    float* hc = (t & 1) ? hA : hB;
    k_gates<<<dim3(48, 7, 2), dim3(256), 0, stream>>>(hp, emb_tgt, tok, Wdx, Wdh, bd, gx, gh);
    k_update_attn<<<dim3(200), dim3(256), 0, stream>>>(gx, gh, hp, hc, ctx, src, cc);
    k_oproj<<<dim3(16, 13), dim3(256), 0, stream>>>(hc, cc, Wo, bo, ob);
    k_gemm_logits<<<dim3(125, 4), dim3(256), 0, stream>>>(ob, Wg, bg, t,
                                                          p_bv, p_bl, p_ml, p_se, p_bi);
    k_reduce_sample<<<dim3(200), dim3(64), 0, stream>>>(p_bv, p_bl, p_ml, p_se, p_bi,
                                                        tgt, t, tok, dead, accb, mc);
  }
  k_final<<<dim3(1), dim3(256), 0, stream>>>(accb, mc, tgt, out);
}

// Round 9
// 6612.320 us; speedup vs baseline: 1.0222x; 1.0222x over previous
//
#include <hip/hip_runtime.h>
#include <stdint.h>

// ---------------------------------------------------------------------------
// MRT seq2seq sampler for MI355X. Round 9: resubmit round-8 kernel unchanged
// (R8 died in infra - GPUAcquisitionTimeout - before reaching hardware).
// R4: 11.4ms. R6 (parallel reduce + oproj retile): 6.55ms, absmax 0.0.
// R7 (64x128 retile): FAILED theory - 91.7us/dispatch (was 86.6), occupancy
// halved (500 blocks), conflicts up. This kernel: R6's 64x64/1000-block
// geometry + global_load_lds width=16 staging (no ds_write, no VGPR
// round-trip, conflict-even linear DMA). LDS: As[64][32], Ws[32][64]
// row-major. FMA order (ascending kk) and 64-col tile partials IDENTICAL
// to R6 -> bit-identical output path. DMA lane-mapping desk-verified twice.
// RNG: JAX threefry2x32, threefry_partitionable=True. VERIFIED r4/r6.
// ---------------------------------------------------------------------------

#define DINLINE __device__ __forceinline__

DINLINE uint32_t rotl32(uint32_t x, int r) { return (x << r) | (x >> (32 - r)); }

// JAX threefry2x32 (jax/_src/prng.py), 20 rounds.
DINLINE void tf2x32(uint32_t k0, uint32_t k1, uint32_t x0, uint32_t x1,
                    uint32_t& y0, uint32_t& y1)
{
  const uint32_t ks2 = k0 ^ k1 ^ 0x1BD11BDAu;
#define TFR(r) { x0 += x1; x1 = rotl32(x1, r); x1 ^= x0; }
  x0 += k0; x1 += k1;
  TFR(13) TFR(15) TFR(26) TFR(6)
  x0 += k1; x1 += ks2 + 1u;
  TFR(17) TFR(29) TFR(16) TFR(24)
  x0 += ks2; x1 += k0 + 2u;
  TFR(13) TFR(15) TFR(26) TFR(6)
  x0 += k0; x1 += k1 + 3u;
  TFR(17) TFR(29) TFR(16) TFR(24)
  x0 += k1; x1 += ks2 + 4u;
  TFR(13) TFR(15) TFR(26) TFR(6)
  x0 += ks2; x1 += k0 + 5u;
#undef TFR
  y0 = x0; y1 = x1;
}

// partitionable random_bits (32-bit): counter = (hi=0, lo=flat), bits = y0^y1
// then uniform(minval=tiny,1) -> gumbel, matching jax gumbel()/uniform() fp32.
DINLINE float gumbel32(uint32_t k0, uint32_t k1, uint32_t flat)
{
  uint32_t b1, b2; tf2x32(k0, k1, 0u, flat, b1, b2);
  const uint32_t bits = b1 ^ b2;
  const float f = __uint_as_float((bits >> 9) | 0x3F800000u) - 1.0f;
  const float u = (f == 0.0f) ? 1.17549435e-38f : f; // max(tiny, f*1+tiny)
  return -logf(-logf(u));
}

DINLINE float sigmoidf_(float x) { return 1.0f / (1.0f + expf(-x)); }

#define PSTRIDE 256   // partials per-row stride (250 col-tiles, padded)

// async global->LDS DMA, 16B per lane. dst is wave-uniform base; HW writes
// dst + lane*16. gsrc is per-lane.
DINLINE void gl_lds16(const float* gsrc, float* lds_base)
{
  __builtin_amdgcn_global_load_lds(
      (const __attribute__((address_space(1))) void*)gsrc,
      (__attribute__((address_space(3))) void*)lds_base, 16, 0, 0);
}

// ---------------------------------------------------------------------------
// init: zero encoder h0
__global__ void k_init(float* __restrict__ henc0)
{
  const int i = blockIdx.x * 256 + threadIdx.x;
  if (i < 1024) henc0[i] = 0.0f;
}

// ---------------------------------------------------------------------------
// Encoder: xg[s*2+b][g] = emb_src[src[s][b]] @ Wex + be   (48 x 1536, K=512)
__global__ __launch_bounds__(256) void k_enc_xg(
    const int* __restrict__ src, const float* __restrict__ emb,
    const float* __restrict__ Wex, const float* __restrict__ be,
    float* __restrict__ xg)
{
  __shared__ float xl[512];
  const int rrow = blockIdx.x;         // s*2+b
  const int tid = threadIdx.x;
  const int tokv = src[rrow];
  for (int i = tid; i < 512; i += 256) xl[i] = emb[(size_t)tokv * 512 + i];
  __syncthreads();
  const int j = blockIdx.y * 256 + tid;
  float a = be[j];
  for (int k = 0; k < 512; ++k) a += xl[k] * Wex[(size_t)k * 1536 + j];
  xg[(size_t)rrow * 1536 + j] = a;
}

// Encoder recurrent step: hout = GRU(x_s, hprev). grid(4) x 256, 2 rows x 128 j.
__global__ __launch_bounds__(256) void k_enc_step(
    const float* __restrict__ hprev, const float* __restrict__ xg,
    const float* __restrict__ Weh, float* __restrict__ hout)
{
  __shared__ float hp[2][512];
  const int tid = threadIdx.x;
  for (int i = tid; i < 1024; i += 256) hp[i >> 9][i & 511] = hprev[i];
  __syncthreads();
  const int row = tid >> 7;                       // 0..1
  const int j = blockIdx.x * 128 + (tid & 127);   // 0..511
  float gz = 0.f, gr = 0.f, gn = 0.f;
  for (int k = 0; k < 512; ++k) {
    const float h = hp[row][k];
    const float* w = Weh + (size_t)k * 1536 + j;
    gz += h * w[0]; gr += h * w[512]; gn += h * w[1024];
  }
  const float xz = xg[row * 1536 + j];
  const float xr = xg[row * 1536 + j + 512];
  const float xn = xg[row * 1536 + j + 1024];
  const float z = sigmoidf_(xz + gz);
  const float r = sigmoidf_(xr + gr);
  const float n = tanhf(xn + r * gn);
  hout[row * 512 + j] = (1.0f - z) * n + z * hp[row][j];
}

// Decoder state init: h = repeat(hT), tok=BOS, dead=0, acc=0, match=1 (BOS hit)
__global__ void k_dec_init(const float* __restrict__ ctx23, float* __restrict__ hA,
                           int* __restrict__ tok, float* __restrict__ dead,
                           float* __restrict__ acc, int* __restrict__ mc)
{
  const int i = blockIdx.x * 256 + threadIdx.x;
  if (i < 200 * 512) {
    const int bn = i >> 9, k = i & 511, b = bn / 100;
    hA[i] = ctx23[b * 512 + k];
  }
  if (i < 200) { tok[i] = 2; dead[i] = 0.f; acc[i] = 0.f; mc[i] = 1; }
}

// ---------------------------------------------------------------------------
// gates GEMM: z=0 -> gx = emb_tgt[tok] @ Wdx + bd ; z=1 -> gh = h @ Wdh
// tiles 32x32, BK=32, 2x2 microtile. grid(48, 7, 2) x 256.
__global__ __launch_bounds__(256) void k_gates(
    const float* __restrict__ hprev, const float* __restrict__ emb_tgt,
    const int* __restrict__ tok,
    const float* __restrict__ Wdx, const float* __restrict__ Wdh,
    const float* __restrict__ bd,
    float* __restrict__ gx, float* __restrict__ gh)
{
  __shared__ float As[32][33];
  __shared__ float Ws[32][32];
  const int tid = threadIdx.x;
  const int nt = blockIdx.x, mt = blockIdx.y, zz = blockIdx.z;
  const int c0 = nt * 32;
  const float* __restrict__ Bw = zz ? Wdh : Wdx;
  float a00 = 0.f, a01 = 0.f, a10 = 0.f, a11 = 0.f;
  const int tr = tid >> 4, tc = tid & 15;
  for (int k0 = 0; k0 < 512; k0 += 32) {
    {
      const int r = tid >> 3, kk = (tid & 7) << 2;
      const int row = mt * 32 + r;
      float4 v = make_float4(0.f, 0.f, 0.f, 0.f);
      if (row < 200) {
        const int k = k0 + kk;
        if (zz == 0) v = *(const float4*)(emb_tgt + (size_t)tok[row] * 512 + k);
        else         v = *(const float4*)(hprev + (size_t)row * 512 + k);
      }
      As[kk + 0][r] = v.x; As[kk + 1][r] = v.y; As[kk + 2][r] = v.z; As[kk + 3][r] = v.w;
    }
    {
      const int kr = tid >> 3, cc = (tid & 7) << 2;
      *(float4*)&Ws[kr][cc] = *(const float4*)(Bw + (size_t)(k0 + kr) * 1536 + c0 + cc);
    }
    __syncthreads();
#pragma unroll
    for (int kk = 0; kk < 32; ++kk) {
      const float a0 = As[kk][tr * 2], a1 = As[kk][tr * 2 + 1];
      const float w0 = Ws[kk][tc * 2], w1 = Ws[kk][tc * 2 + 1];
      a00 += a0 * w0; a01 += a0 * w1; a10 += a1 * w0; a11 += a1 * w1;
    }
    __syncthreads();
  }
  float* __restrict__ outp = zz ? gh : gx;
  const int row0 = mt * 32 + tr * 2, col0 = c0 + tc * 2;
  const float b0 = zz ? 0.f : bd[col0];
  const float b1 = zz ? 0.f : bd[col0 + 1];
  if (row0 < 200) {
    outp[(size_t)row0 * 1536 + col0]     = a00 + b0;
    outp[(size_t)row0 * 1536 + col0 + 1] = a01 + b1;
  }
  if (row0 + 1 < 200) {
    outp[(size_t)(row0 + 1) * 1536 + col0]     = a10 + b0;
    outp[(size_t)(row0 + 1) * 1536 + col0 + 1] = a11 + b1;
  }
}

// ---------------------------------------------------------------------------
// Per-row: GRU combine -> h_t, then attention softmax over S=24 -> context c.
// grid(200) x 256.
__global__ __launch_bounds__(256) void k_update_attn(
    const float* __restrict__ gx, const float* __restrict__ gh,
    const float* __restrict__ hprev, float* __restrict__ hcur,
    const float* __restrict__ ctx, const int* __restrict__ src,
    float* __restrict__ cc)
{
  const int bn = blockIdx.x, b = bn / 100;
  const int tid = threadIdx.x;
  __shared__ float hn[512];
  __shared__ float sc[24];
  const float* gxr = gx + (size_t)bn * 1536;
  const float* ghr = gh + (size_t)bn * 1536;
  const float* hpr = hprev + (size_t)bn * 512;
  for (int j = tid; j < 512; j += 256) {
    const float z = sigmoidf_(gxr[j] + ghr[j]);
    const float r = sigmoidf_(gxr[j + 512] + ghr[j + 512]);
    const float n = tanhf(gxr[j + 1024] + r * ghr[j + 1024]);
    const float h = (1.0f - z) * n + z * hpr[j];
    hn[j] = h;
    hcur[(size_t)bn * 512 + j] = h;
  }
  __syncthreads();
  const int w = tid >> 6, lane = tid & 63;
  for (int s = w; s < 24; s += 4) {
    const float* cr = ctx + (size_t)(s * 2 + b) * 512;
    float v = 0.f;
#pragma unroll
    for (int m = 0; m < 8; ++m) { const int k = lane + 64 * m; v += hn[k] * cr[k]; }
#pragma unroll
    for (int m2 = 32; m2 >= 1; m2 >>= 1) v += __shfl_xor(v, m2, 64);
    if (lane == 0) sc[s] = (src[s * 2 + b] == 0) ? -1e9f : v;  // pad mask (NEG_INF)
  }
  __syncthreads();
  float mx = -3.0e38f;
#pragma unroll
  for (int s = 0; s < 24; ++s) mx = fmaxf(mx, sc[s]);
  float ez[24]; float sum = 0.f;
#pragma unroll
  for (int s = 0; s < 24; ++s) { ez[s] = expf(sc[s] - mx); sum += ez[s]; }
#pragma unroll
  for (int s = 0; s < 24; ++s) ez[s] = ez[s] / sum;  // attn, rounded like reference
  for (int j = tid; j < 512; j += 256) {
    float a = 0.f;
#pragma unroll
    for (int s = 0; s < 24; ++s) a += ez[s] * ctx[(size_t)(s * 2 + b) * 512 + j];
    cc[(size_t)bn * 512 + j] = a;
  }
}

// ---------------------------------------------------------------------------
// o = tanh([h|c] @ Wo + bo). 16x32 tiles, K=1024, 2 outputs/thread.
// grid(16, 13) x 256 = 208 blocks. Bit-identical ob vs r4 (K-order unchanged).
__global__ __launch_bounds__(256) void k_oproj(
    const float* __restrict__ hcur, const float* __restrict__ ccx,
    const float* __restrict__ Wo, const float* __restrict__ bo,
    float* __restrict__ ob)
{
  __shared__ float As[32][17];   // [kk][row], 17 stride: conflict-free
  __shared__ float Ws[32][32];   // [kk][col]
  const int tid = threadIdx.x;
  const int nt = blockIdx.x, mt = blockIdx.y;
  const int c0 = nt * 32, r0 = mt * 16;
  const int tr = tid >> 4, tc = tid & 15;      // row 0..15, col-pair 0..15
  float a0 = 0.f, a1 = 0.f;
  for (int k0 = 0; k0 < 1024; k0 += 32) {
    {
      const int kk = tid & 31;                 // 0..31
      const int rr = tid >> 5;                 // 0..7
      const int k = k0 + kk;
      const float* srcp = (k < 512) ? (hcur + k) : (ccx + (k - 512));
      for (int r = rr; r < 16; r += 8) {
        const int row = r0 + r;
        As[kk][r] = (row < 200) ? srcp[(size_t)row * 512] : 0.f;
      }
    }
    {
      const int kr = tid >> 3, cc = (tid & 7) << 2;
      *(float4*)&Ws[kr][cc] = *(const float4*)(Wo + (size_t)(k0 + kr) * 512 + c0 + cc);
    }
    __syncthreads();
#pragma unroll
    for (int kk = 0; kk < 32; ++kk) {
      const float a = As[kk][tr];
      a0 += a * Ws[kk][tc * 2];
      a1 += a * Ws[kk][tc * 2 + 1];
    }
    __syncthreads();
  }
  const int row = r0 + tr, col = c0 + tc * 2;
  if (row < 200) {
    ob[(size_t)row * 512 + col]     = tanhf(a0 + bo[col]);
    ob[(size_t)row * 512 + col + 1] = tanhf(a1 + bo[col + 1]);
  }
}

// ---------------------------------------------------------------------------
// logits = o @ Wg + bg, fused gumbel + per-tile argmax / max / sumexp partials.
// 64x64 tile, BK=32, 4x4 microtile (= R6 geometry, 1000 blocks) but staging
// via global_load_lds width=16 (no ds_write, no VGPR round-trip).
// As[64][32] row-major, Ws[32][64] row-major (linear, DMA-required layouts).
// Per-output FMA order (ascending kk) and 64-col partial grouping IDENTICAL
// to R6 -> bit-identical results. Rows>=200 clamp to 199 (epilogue guards).
__global__ __launch_bounds__(256) void k_gemm_logits(
    const float* __restrict__ Ao, const float* __restrict__ Wg,
    const float* __restrict__ bg, int t,
    float* __restrict__ p_bv, float* __restrict__ p_bl,
    float* __restrict__ p_ml, float* __restrict__ p_se, int* __restrict__ p_bi)
{
  __shared__ float As[64 * 32];   // [row][k] row-major
  __shared__ float Ws[32 * 64];   // [kk][col] row-major
  const int tid = threadIdx.x;
  const int wid = tid >> 6;       // wave 0..3 (uniform within wave)
  const int lane = tid & 63;
  const int nt = blockIdx.x, mt = blockIdx.y;
  const int c0 = nt * 64, r0 = mt * 64;
  const int tr = tid >> 4, tc = tid & 15;
  float acc[4][4] = {};

  // per-lane DMA source decomposition (loop-invariant)
  const int arl = wid * 8 + (lane >> 3);        // A local row (p=0); p=1 adds 32
  const int aq  = (lane & 7) << 2;              // A k-offset (floats)
  const int wkk = wid * 8 + (lane >> 4);        // W local kk (j=0); j=1 adds 4
  const int wc  = (lane & 15) << 2;             // W col offset (floats)
  int rowA0 = r0 + arl;       if (rowA0 > 199) rowA0 = 199;
  int rowA1 = r0 + 32 + arl;  if (rowA1 > 199) rowA1 = 199;
  const float* gA0 = Ao + (size_t)rowA0 * 512 + aq;
  const float* gA1 = Ao + (size_t)rowA1 * 512 + aq;
  const float* gW0 = Wg + (size_t)wkk * 16000 + c0 + wc;
  const float* gW1 = Wg + (size_t)(wkk + 4) * 16000 + c0 + wc;
  float* lA0 = As + wid * 256;          // wave-uniform LDS bases
  float* lA1 = As + 1024 + wid * 256;
  float* lW0 = Ws + (wid * 8) * 64;
  float* lW1 = Ws + (wid * 8 + 4) * 64;

  for (int k0 = 0; k0 < 512; k0 += 32) {
    gl_lds16(gA0 + k0, lA0);
    gl_lds16(gA1 + k0, lA1);
    gl_lds16(gW0 + (size_t)k0 * 16000, lW0);
    gl_lds16(gW1 + (size_t)k0 * 16000, lW1);
    __syncthreads();
#pragma unroll
    for (int kk = 0; kk < 32; kk += 4) {
      const float4 a0 = *(const float4*)&As[(tr * 4 + 0) * 32 + kk];
      const float4 a1 = *(const float4*)&As[(tr * 4 + 1) * 32 + kk];
      const float4 a2 = *(const float4*)&As[(tr * 4 + 2) * 32 + kk];
      const float4 a3 = *(const float4*)&As[(tr * 4 + 3) * 32 + kk];
      const float a0v[4] = {a0.x, a0.y, a0.z, a0.w};
      const float a1v[4] = {a1.x, a1.y, a1.z, a1.w};
      const float a2v[4] = {a2.x, a2.y, a2.z, a2.w};
      const float a3v[4] = {a3.x, a3.y, a3.z, a3.w};
#pragma unroll
      for (int k2 = 0; k2 < 4; ++k2) {
        const float4 w = *(const float4*)&Ws[(kk + k2) * 64 + (tc << 2)];
        const float wv[4] = {w.x, w.y, w.z, w.w};
#pragma unroll
        for (int j = 0; j < 4; ++j) {
          acc[0][j] += a0v[k2] * wv[j];
          acc[1][j] += a1v[k2] * wv[j];
          acc[2][j] += a2v[k2] * wv[j];
          acc[3][j] += a3v[k2] * wv[j];
        }
      }
    }
    __syncthreads();
  }
  // epilogue: gumbel + per-row tile reductions over the 64-col tile (as R6)
  uint32_t sk0, sk1; tf2x32(0u, 42u, 0u, (uint32_t)t, sk0, sk1); // split(key(42))[t]
  const float NEGINF = -3.0e38f;
#pragma unroll
  for (int i = 0; i < 4; ++i) {
    const int row = r0 + (tr << 2) + i;
    const bool valid = (row < 200);
    float logit[4];
    float tmax = NEGINF;
#pragma unroll
    for (int j = 0; j < 4; ++j) {
      const int col = c0 + (tc << 2) + j;
      logit[j] = acc[i][j] + bg[col];
      tmax = fmaxf(tmax, logit[j]);
    }
    if (!valid) tmax = NEGINF;
#pragma unroll
    for (int m = 1; m <= 8; m <<= 1) tmax = fmaxf(tmax, __shfl_xor(tmax, m, 64));
    float se = 0.f, bv = NEGINF, bl = 0.f; int bi = 0;
    if (valid) {
#pragma unroll
      for (int j = 0; j < 4; ++j) {
        const int col = c0 + (tc << 2) + j;
        se += expf(logit[j] - tmax);
        const float g = gumbel32(sk0, sk1, (uint32_t)(row * 16000 + col));
        const float v = logit[j] + g;
        if (v > bv) { bv = v; bi = col; bl = logit[j]; }  // first-occurrence ties
      }
    }
#pragma unroll
    for (int m = 1; m <= 8; m <<= 1) {
      const float ov = __shfl_xor(bv, m, 64);
      const int   oi = __shfl_xor(bi, m, 64);
      const float ol = __shfl_xor(bl, m, 64);
      se += __shfl_xor(se, m, 64);
      if (ov > bv || (ov == bv && oi < bi)) { bv = ov; bi = oi; bl = ol; }
    }
    if (tc == 0 && valid) {
      const size_t p = (size_t)row * PSTRIDE + nt;   // bn-major for coalesced reduce
      p_bv[p] = bv; p_bl[p] = bl; p_ml[p] = tmax; p_se[p] = se; p_bi[p] = bi;
    }
  }
}

// ---------------------------------------------------------------------------
// Parallel combine of 250 tile-partials per row. grid(200) x 64 (one wave/bn).
// Global max M: exact. Argmax: exact (max + lower-index tie-break).
// Denominator S: tree order (tolerant path; verified absmax 0.0 in r6).
__global__ void k_reduce_sample(
    const float* __restrict__ p_bv, const float* __restrict__ p_bl,
    const float* __restrict__ p_ml, const float* __restrict__ p_se,
    const int* __restrict__ p_bi,
    const int* __restrict__ tgt, int t,
    int* __restrict__ tok, float* __restrict__ dead,
    float* __restrict__ acc, int* __restrict__ mc)
{
  const int bn = blockIdx.x;
  const int lane = threadIdx.x;                 // 0..63
  const size_t base = (size_t)bn * PSTRIDE;
  float M = -3.0e38f;
  for (int nt = lane; nt < 250; nt += 64) M = fmaxf(M, p_ml[base + nt]);
#pragma unroll
  for (int m = 32; m >= 1; m >>= 1) M = fmaxf(M, __shfl_xor(M, m, 64));
  float S = 0.f, bv = -3.0e38f, bl = 0.f;
  int bi = 0x7FFFFFFF;
  for (int nt = lane; nt < 250; nt += 64) {
    S += p_se[base + nt] * expf(p_ml[base + nt] - M);
    const float v = p_bv[base + nt];
    const int   i = p_bi[base + nt];
    if (v > bv || (v == bv && i < bi)) { bv = v; bi = i; bl = p_bl[base + nt]; }
  }
#pragma unroll
  for (int m = 32; m >= 1; m >>= 1) {
    S += __shfl_xor(S, m, 64);
    const float ov = __shfl_xor(bv, m, 64);
    const int   oi = __shfl_xor(bi, m, 64);
    const float ol = __shfl_xor(bl, m, 64);
    if (ov > bv || (ov == bv && oi < bi)) { bv = ov; bi = oi; bl = ol; }
  }
  if (lane == 0) {
    const float dv = dead[bn];
    acc[bn] += ((bl - M) - logf(S)) * (1.0f - dv);   // logp[nxt]*(1-dead)
    const int b = bn / 100;
    if (t + 1 < 26) {
      const int tv = tgt[(t + 1) * 2 + b];
      if (tv != 0 && bi == tv) mc[bn] += 1;
    }
    dead[bn] = fmaxf(dv, (bi == 3) ? 1.0f : 0.0f);   // EOS=3
    tok[bn] = bi;
  }
}

// ---------------------------------------------------------------------------
// Final: bleu, per-batch softmax over N=100 of acc*ALPHA, 4 scalar outputs.
__global__ __launch_bounds__(256) void k_final(
    const float* __restrict__ accb, const int* __restrict__ mc,
    const int* __restrict__ tgt, float* __restrict__ out)
{
  __shared__ int ncw[4];
  __shared__ float LS[2], SS[2], QS[2];
  const int tid = threadIdx.x, w = tid >> 6, lane = tid & 63;
  int c0c = 0, c1c = 0;
  for (int tt = 0; tt < 26; ++tt) {
    c0c += (tgt[tt * 2] != 0);
    c1c += (tgt[tt * 2 + 1] != 0);
  }
  int nc = (tid < 200) ? mc[tid] : 0;
#pragma unroll
  for (int m = 32; m >= 1; m >>= 1) nc += __shfl_xor(nc, m, 64);
  if (lane == 0) ncw[w] = nc;
  if (w < 2) {
    const int b = w;
    const float denom = fmaxf((float)(b == 0 ? c0c : c1c), 1.0f);
    const float e0 = accb[b * 100 + lane] * 0.005f;
    const float e1 = (lane < 36) ? accb[b * 100 + 64 + lane] * 0.005f : -3.0e38f;
    float mx = fmaxf(e0, e1);
#pragma unroll
    for (int m = 32; m >= 1; m >>= 1) mx = fmaxf(mx, __shfl_xor(mx, m, 64));
    float S = 0.f, L = 0.f, Q = 0.f;
    {
      const float p = expf(e0 - mx);
      const float bl = (float)mc[b * 100 + lane] / denom;
      S += p; L += bl * p; Q += bl * bl * p;
    }
    if (lane < 36) {
      const float p = expf(e1 - mx);
      const float bl = (float)mc[b * 100 + 64 + lane] / denom;
      S += p; L += bl * p; Q += bl * bl * p;
    }
#pragma unroll
    for (int m = 32; m >= 1; m >>= 1) {
      S += __shfl_xor(S, m, 64);
      L += __shfl_xor(L, m, 64);
      Q += __shfl_xor(Q, m, 64);
    }
    if (lane == 0) { LS[b] = L; SS[b] = S; QS[b] = Q; }
  }
  __syncthreads();
  if (tid == 0) {
    out[0] = -(LS[0] / SS[0] + LS[1] / SS[1]);  // totalLoss
    out[1] =  QS[0] / SS[0] + QS[1] / SS[1];    // secondMoment
    out[2] = 100.0f * (float)(c0c + c1c);       // numWords
    out[3] = (float)(ncw[0] + ncw[1] + ncw[2] + ncw[3]);  // numCorrect
  }
}

// ---------------------------------------------------------------------------
extern "C" void kernel_launch(void* const* d_in, const int* in_sizes, int n_in,
                              void* d_out, int out_size, void* d_ws, size_t ws_size,
                              hipStream_t stream)
{
  (void)in_sizes; (void)n_in; (void)out_size; (void)ws_size;
  const int*   src     = (const int*)  d_in[0];
  const int*   tgt     = (const int*)  d_in[1];
  // d_in[2] lengths: unused by the reference math
  const float* emb_src = (const float*)d_in[3];
  const float* emb_tgt = (const float*)d_in[4];
  const float* Wex     = (const float*)d_in[5];
  const float* Weh     = (const float*)d_in[6];
  const float* be      = (const float*)d_in[7];
  const float* Wdx     = (const float*)d_in[8];
  const float* Wdh     = (const float*)d_in[9];
  const float* bd      = (const float*)d_in[10];
  const float* Wo      = (const float*)d_in[11];
  const float* bo      = (const float*)d_in[12];
  const float* Wg      = (const float*)d_in[13];
  const float* bg      = (const float*)d_in[14];
  float* out = (float*)d_out;

  float* W = (float*)d_ws;
  size_t off = 0;
  auto alloc = [&](size_t n) { float* p = W + off; off += n; return p; };
  float* henc0 = alloc(1024);
  float* xgE   = alloc(48 * 1536);
  float* ctx   = alloc(24 * 1024);
  float* hA    = alloc(200 * 512);
  float* hB    = alloc(200 * 512);
  float* gx    = alloc(200 * 1536);
  float* gh    = alloc(200 * 1536);
  float* cc    = alloc(200 * 512);
  float* ob    = alloc(200 * 512);
  float* p_bv  = alloc(200 * PSTRIDE);
  float* p_bl  = alloc(200 * PSTRIDE);
  float* p_ml  = alloc(200 * PSTRIDE);
  float* p_se  = alloc(200 * PSTRIDE);
  int*   p_bi  = (int*)alloc(200 * PSTRIDE);
  int*   tok   = (int*)alloc(200);
  float* dead  = alloc(200);
  float* accb  = alloc(200);
  int*   mc    = (int*)alloc(200);
  // total ~5.6 MB of d_ws

  // --- encoder ---
  k_init<<<dim3(4), dim3(256), 0, stream>>>(henc0);
  k_enc_xg<<<dim3(48, 6), dim3(256), 0, stream>>>(src, emb_src, Wex, be, xgE);
  for (int s = 0; s < 24; ++s) {
    const float* hp = (s == 0) ? henc0 : (ctx + (size_t)(s - 1) * 1024);
    k_enc_step<<<dim3(4), dim3(256), 0, stream>>>(
        hp, xgE + (size_t)s * 2 * 1536, Weh, ctx + (size_t)s * 1024);
  }
  k_dec_init<<<dim3(400), dim3(256), 0, stream>>>(ctx + 23 * 1024, hA, tok, dead, accb, mc);

  // --- decoder: 37 sequential sampled steps ---
  for (int t = 0; t < 37; ++t) {
    float* hp = (t & 1) ? hB : hA;
    float* hc = (t & 1) ? hA : hB;
    k_gates<<<dim3(48, 7, 2), dim3(256), 0, stream>>>(hp, emb_tgt, tok, Wdx, Wdh, bd, gx, gh);
    k_update_attn<<<dim3(200), dim3(256), 0, stream>>>(gx, gh, hp, hc, ctx, src, cc);
    k_oproj<<<dim3(16, 13), dim3(256), 0, stream>>>(hc, cc, Wo, bo, ob);
    k_gemm_logits<<<dim3(250, 4), dim3(256), 0, stream>>>(ob, Wg, bg, t,
                                                          p_bv, p_bl, p_ml, p_se, p_bi);
    k_reduce_sample<<<dim3(200), dim3(64), 0, stream>>>(p_bv, p_bl, p_ml, p_se, p_bi,
                                                        tgt, t, tok, dead, accb, mc);
  }
  k_final<<<dim3(1), dim3(256), 0, stream>>>(accb, mc, tgt, out);
}